// Round 11
// baseline (222.933 us; speedup 1.0000x reference)
//
#include <hip/hip_runtime.h>
#include <hip/hip_bf16.h>
#include <cstdint>
#include <cstddef>

// x[1024][512] f32, hidden_w[19200][512] f32, hidden_b[19200] f32,
// out_w[10][19200] f32, out_b[80][10] f32, neuron_model_id[19200] i32
// (deterministic; recomputed on device). out[1024][80][10] f32.

typedef unsigned short u16;
typedef unsigned int u32;
typedef __bf16 bf16x8 __attribute__((ext_vector_type(8)));
typedef float f32x4 __attribute__((ext_vector_type(4)));

__device__ __forceinline__ u16 f2bf(float f) {
  u32 u = __builtin_bit_cast(u32, f);
  u += 0x7fffu + ((u >> 16) & 1u);   // RNE
  return (u16)(u >> 16);
}

__device__ __forceinline__ void async16(void* l, const void* g) {
  __builtin_amdgcn_global_load_lds(
      (__attribute__((address_space(1))) void*)(void*)g,
      (__attribute__((address_space(3))) void*)l, 16, 0, 0);
}

// ---------------- kernel 0: fp32 -> bf16 convert (x and hidden_w) ------------
__global__ __launch_bounds__(256) void cvt_kernel(
    const float4* __restrict__ xs, uint2* __restrict__ xd, int nx4,
    const float4* __restrict__ ws, uint2* __restrict__ wd, int nw4) {
  int i = blockIdx.x * blockDim.x + threadIdx.x;
  if (i >= nx4 + nw4) return;
  const float4* s; uint2* d; int j;
  if (i < nx4) { s = xs; d = xd; j = i; }
  else         { s = ws; d = wd; j = i - nx4; }
  float4 f = s[j];
  uint2 o;
  o.x = (u32)f2bf(f.x) | ((u32)f2bf(f.y) << 16);
  o.y = (u32)f2bf(f.z) | ((u32)f2bf(f.w) << 16);
  d[j] = o;
}

// ---------------- kernel 1: bf16 GEMM (x @ W^T + b) with fused activation ----
// 128x128 tile, BK=32 double-buffered -> 32 KB LDS -> 5 blocks/CU (R10 was
// 64 KB -> 2 blocks/CU, Occ 14.8%, latency-bound: dur insensitive to FETCH
// 82->17.5 MB and conflicts 0->7.4M; occupancy is the binding constraint).
// 64B-row LDS swizzle: chunk c = q ^ ((row>>1)&3). Each consecutive-8-lane
// group of a ds_read_b128 covers all 32 banks exactly once -> conflict-free.
// Source pre-swizzled, linear LDS dest (global_load_lds writes base+lane*16),
// swizzled read (both-sides-or-neither rule).
// XCD-chunked block mapping (R7/R10-verified: FETCH 82->17.5 MB); 150 blocks
// per XCD and 160 resident slots -> whole XCD panel-set co-resident.
// Counted-vmcnt pipeline (R10-verified, tripwire-clean): 3 K-tiles in flight,
// never drain to 0 in the loop.
__global__ __launch_bounds__(256, 5) void gemm_act_kernel(
    const u16* __restrict__ A,
    const u16* __restrict__ Bw,
    const float* __restrict__ hbias,
    u16* __restrict__ aout) {
  __shared__ char lds[32768];  // A: 2 x 8KB @0, B: 2 x 8KB @16384
  const int t = threadIdx.x;
  const int lane = t & 63;
  const int w = t >> 6;
  const int c = blockIdx.x & 7;
  const int L = c * 150 + (blockIdx.x >> 3);
  const int bx = L >> 3;            // N tile 0..149
  const int by = L & 7;             // M tile 0..7
  const int row0 = by * 128;
  const int col0 = bx * 128;
  const int wr = w >> 1, wc = w & 1;

  f32x4 acc[4][4];
#pragma unroll
  for (int m = 0; m < 4; ++m)
#pragma unroll
    for (int n = 0; n < 4; ++n)
#pragma unroll
      for (int r = 0; r < 4; ++r) acc[m][n][r] = 0.f;

  const int srow = t >> 2;  // 0..63 (row within half-tile)
  const int sc4 = t & 3;    // 16B chunk within 64B row

  auto stage = [&](int buf, int kt) {
    const int c4 = sc4 ^ ((srow >> 1) & 3);     // inverse-swizzled source
    const int k0 = kt * 32 + c4 * 8;
#pragma unroll
    for (int i = 0; i < 2; ++i) {
      int row = i * 64 + srow;
      // dest linear: i*4096 + w*1024 (+ lane*16 by HW) == row*64 + sc4*16
      async16(lds + buf * 8192 + i * 4096 + w * 1024,
              A + (size_t)(row0 + row) * 512 + k0);
      async16(lds + 16384 + buf * 8192 + i * 4096 + w * 1024,
              Bw + (size_t)(col0 + row) * 512 + k0);
    }
  };

  const int il = lane & 15, q = lane >> 4;

  auto compute = [&](int buf) {
    const char* bA = lds + buf * 8192;
    const char* bB = lds + 16384 + buf * 8192;
    bf16x8 av[4], bv[4];
#pragma unroll
    for (int m = 0; m < 4; ++m) {
      int row = wr * 64 + m * 16 + il;
      av[m] = *(const bf16x8*)(bA + row * 64 +
                               ((q * 16) ^ (((row >> 1) & 3) << 4)));
    }
#pragma unroll
    for (int n = 0; n < 4; ++n) {
      int row = wc * 64 + n * 16 + il;
      bv[n] = *(const bf16x8*)(bB + row * 64 +
                               ((q * 16) ^ (((row >> 1) & 3) << 4)));
    }
#pragma unroll
    for (int m = 0; m < 4; ++m)
#pragma unroll
      for (int n = 0; n < 4; ++n)
        acc[m][n] = __builtin_amdgcn_mfma_f32_16x16x32_bf16(av[m], bv[n],
                                                            acc[m][n], 0, 0, 0);
  };

  // Pipeline: tiles kt and kt+1 in flight entering iteration kt.
  stage(0, 0);   // 4 loads/thread
  stage(1, 1);   // 4 more (8 outstanding)
#pragma unroll 4
  for (int kt = 0; kt < 16; ++kt) {
    if (kt < 15) asm volatile("s_waitcnt vmcnt(4)" ::: "memory");  // cur landed
    else         asm volatile("s_waitcnt vmcnt(0)" ::: "memory");  // last tile
    __builtin_amdgcn_s_barrier();      // all waves' cur loads visible
    compute(kt & 1);
    asm volatile("" ::: "memory");
    __builtin_amdgcn_s_barrier();      // all waves done reading cur
    if (kt < 14) stage(kt & 1, kt + 2); // refill cur's buffer with tile kt+2
  }

  // epilogue: bias + activation (uniform per 16-wide fragment: 4800 % 16 == 0)
#pragma unroll
  for (int n = 0; n < 4; ++n) {
    int gcol = col0 + wc * 64 + n * 16 + il;
    int act = gcol / 4800;  // 0:relu 1:tanh 2:sigmoid 3:gelu(exact)
    float bias = hbias[gcol];
#pragma unroll
    for (int m = 0; m < 4; ++m) {
      int growb = row0 + wr * 64 + m * 16 + q * 4;
#pragma unroll
      for (int r = 0; r < 4; ++r) {
        float v = acc[m][n][r] + bias;
        float o;
        if (act == 0)      o = fmaxf(v, 0.f);
        else if (act == 1) {                      // tanh via hw exp
          float e = __expf(-2.f * fabsf(v));
          o = copysignf((1.f - e) / (1.f + e), v);
        }
        else if (act == 2) o = 1.f / (1.f + __expf(-v));
        else               o = 0.5f * v * (1.f + erff(v * 0.70710678118f));
        aout[(size_t)(growb + r) * 19200 + gcol] = f2bf(o);
      }
    }
  }
}

// ---------------- kernel 2: ragged out-projection via MFMA -------------------
// Per block: one model x 64 batch rows (4 waves x 16 rows). Per wave:
// out[16b x 10o] = sum_k a[b][k] * ow[o][k] via mfma_f32_16x16x32_bf16.
// K in {64,128,256,512} -> always a multiple of 64: unroll 2 with独立 dual
// accumulator chains for ILP on the latency-bound 16x64B gather.
__global__ __launch_bounds__(256) void layer2_kernel(
    const u16* __restrict__ a,    // [1024][19200] bf16
    const float* __restrict__ ow, // [10][19200] f32
    const float* __restrict__ ob, // [80][10] f32
    float* __restrict__ out) {    // [1024][80][10] f32
  const int t = threadIdx.x;
  const int lane = t & 63;
  const int w = t >> 6;
  const int m = blockIdx.x % 80;   // model (interleaved for load balance)
  const int bt = blockIdx.x / 80;  // batch tile 0..15
  const int b0 = bt * 64 + w * 16;
  const int s = m & 3;
  const int rep = (m >> 2) % 5;
  const int act = m / 20;
  const int seg0 = act * 4800 + rep * 960 + 64 * ((1 << s) - 1);
  const int K = 64 << s;
  const int il = lane & 15, q = lane >> 4;

  f32x4 acc0 = {0.f, 0.f, 0.f, 0.f};
  f32x4 acc1 = {0.f, 0.f, 0.f, 0.f};
  const u16* arow = a + (size_t)(b0 + il) * 19200 + seg0 + q * 8;
  const float* wrow = ow + il * 19200 + seg0 + q * 8;  // deref only when il<10
  const bool wvalid = il < 10;

  for (int k0 = 0; k0 < K; k0 += 64) {
    bf16x8 af0 = *(const bf16x8*)(arow + k0);
    bf16x8 af1 = *(const bf16x8*)(arow + k0 + 32);
    union { bf16x8 v; u16 u[8]; } b0u, b1u;
    if (wvalid) {
      float4 f0 = *(const float4*)(wrow + k0);
      float4 f1 = *(const float4*)(wrow + k0 + 4);
      float4 f2 = *(const float4*)(wrow + k0 + 32);
      float4 f3 = *(const float4*)(wrow + k0 + 36);
      b0u.u[0] = f2bf(f0.x); b0u.u[1] = f2bf(f0.y);
      b0u.u[2] = f2bf(f0.z); b0u.u[3] = f2bf(f0.w);
      b0u.u[4] = f2bf(f1.x); b0u.u[5] = f2bf(f1.y);
      b0u.u[6] = f2bf(f1.z); b0u.u[7] = f2bf(f1.w);
      b1u.u[0] = f2bf(f2.x); b1u.u[1] = f2bf(f2.y);
      b1u.u[2] = f2bf(f2.z); b1u.u[3] = f2bf(f2.w);
      b1u.u[4] = f2bf(f3.x); b1u.u[5] = f2bf(f3.y);
      b1u.u[6] = f2bf(f3.z); b1u.u[7] = f2bf(f3.w);
    } else {
#pragma unroll
      for (int j = 0; j < 8; ++j) { b0u.u[j] = 0; b1u.u[j] = 0; }
    }
    acc0 = __builtin_amdgcn_mfma_f32_16x16x32_bf16(af0, b0u.v, acc0, 0, 0, 0);
    acc1 = __builtin_amdgcn_mfma_f32_16x16x32_bf16(af1, b1u.v, acc1, 0, 0, 0);
  }

  if (il < 10) {
    float bias = ob[m * 10 + il];
#pragma unroll
    for (int r = 0; r < 4; ++r)
      out[(size_t)(b0 + q * 4 + r) * 800 + m * 10 + il] = acc0[r] + acc1[r] + bias;
  }
}

extern "C" void kernel_launch(void* const* d_in, const int* in_sizes, int n_in,
                              void* d_out, int out_size, void* d_ws, size_t ws_size,
                              hipStream_t stream) {
  const float* x = (const float*)d_in[0];
  const float* hw = (const float*)d_in[1];
  const float* hb = (const float*)d_in[2];
  const float* ow = (const float*)d_in[3];
  const float* ob = (const float*)d_in[4];
  float* out = (float*)d_out;

  // workspace layout: x_bf16 (1 MB) | w_bf16 (19.66 MB) | a_bf16 (39.32 MB)
  char* ws = (char*)d_ws;
  u16* xb = (u16*)ws;
  u16* wb = (u16*)(ws + 1048576);
  u16* ab = (u16*)(ws + 1048576 + 19660800);

  const int nx4 = (1024 * 512) / 4;    // 131072
  const int nw4 = (19200 * 512) / 4;   // 2457600
  const int tot = nx4 + nw4;           // 2588672 = 10112*256
  cvt_kernel<<<tot / 256, 256, 0, stream>>>((const float4*)x, (uint2*)xb, nx4,
                                            (const float4*)hw, (uint2*)wb, nw4);
  gemm_act_kernel<<<1200, 256, 0, stream>>>(xb, wb, hb, ab);
  layer2_kernel<<<1280, 256, 0, stream>>>(ab, ow, ob, out);
}